// Round 9
// baseline (181.662 us; speedup 1.0000x reference)
//
#include <hip/hip_runtime.h>

#define NPIX (512*512)
#define NIMG 32
#define CTR 255.5f
#define NCH 128           // chunks (blocks) per image
#define NTHR 256
#define NP1 12

__device__ __forceinline__ double wredd(double v) {
#pragma unroll
    for (int off = 32; off; off >>= 1) v += __shfl_down(v, off, 64);
    return v;
}

__device__ __forceinline__ double aload(const double* p) {
    return __hip_atomic_load(p, __ATOMIC_RELAXED, __HIP_MEMORY_SCOPE_AGENT);
}

// K1: raw moments, 4096 blocks x 256 thr, 8 px/thread (6 float4 batched).
// Block 0 also zeroes the arrival counters used by k2fin (k2 starts only
// after k1 fully drains, so no race).
__global__ __launch_bounds__(NTHR) void k1(const float* __restrict__ x,
                                           double* __restrict__ p1,
                                           int* __restrict__ ctr) {
    if (blockIdx.x == 0 && threadIdx.x < 64) ctr[threadIdx.x] = 0;

    int img = blockIdx.x >> 7;            // / NCH
    int chunk = blockIdx.x & (NCH - 1);
    size_t cb = (size_t)chunk * (NPIX / NCH);   // 2048 px per chunk
    const float* xr = x + (size_t)img * 3 * NPIX;

    float4 Rv[2], Gv[2], Bv[2];
#pragma unroll
    for (int j = 0; j < 2; ++j) {
        size_t off = cb + ((size_t)j * NTHR + threadIdx.x) * 4;
        Rv[j] = *(const float4*)(xr + off);
        Gv[j] = *(const float4*)(xr + NPIX + off);
        Bv[j] = *(const float4*)(xr + 2 * NPIX + off);
    }

    float A[11];
#pragma unroll
    for (int a = 0; a < 11; ++a) A[a] = 0.0f;

#pragma unroll
    for (int j = 0; j < 2; ++j) {
        size_t off = cb + ((size_t)j * NTHR + threadIdx.x) * 4;
        float gv[4];
        gv[0] = 0.299f * Rv[j].x + 0.587f * Gv[j].x + 0.114f * Bv[j].x;
        gv[1] = 0.299f * Rv[j].y + 0.587f * Gv[j].y + 0.114f * Bv[j].y;
        gv[2] = 0.299f * Rv[j].z + 0.587f * Gv[j].z + 0.114f * Bv[j].z;
        gv[3] = 0.299f * Rv[j].w + 0.587f * Gv[j].w + 0.114f * Bv[j].w;
        float v = (float)(int)(off >> 9) - CTR;
        float v2 = v * v, v3 = v2 * v;
        float u0 = (float)(int)(off & 511) - CTR;
#pragma unroll
        for (int u = 0; u < 4; ++u) {
            float gg = gv[u];
            float uu = u0 + (float)u;
            float t1 = gg * uu, t2 = t1 * uu, t3 = t2 * uu;
            A[0] += gg;
            A[1] += gg * gg;
            A[2] += t1;
            A[3] += gg * v;
            A[4] += t2;
            A[5] += t1 * v;
            A[6] += gg * v2;
            A[7] += t3;
            A[8] += t2 * v;
            A[9] += t1 * v2;
            A[10] += gg * v3;
        }
    }

    __shared__ double lds[4][11];
    int lane = threadIdx.x & 63, wv = threadIdx.x >> 6;
#pragma unroll
    for (int a = 0; a < 11; ++a) {
        double s = wredd((double)A[a]);
        if (lane == 0) lds[wv][a] = s;
    }
    __syncthreads();
    if (threadIdx.x < 11)
        p1[((size_t)img * NCH + chunk) * NP1 + threadIdx.x] =
            lds[0][threadIdx.x] + lds[1][threadIdx.x] + lds[2][threadIdx.x] + lds[3][threadIdx.x];
}

// K2fin: |g-mean| partials; the 128th-arriving block of each image finalizes.
__global__ __launch_bounds__(NTHR) void k2fin(const float* __restrict__ x,
                                              const double* __restrict__ p1,
                                              double* __restrict__ p2,
                                              int* __restrict__ ctr,
                                              float* __restrict__ out) {
    int img = blockIdx.x >> 7;
    int chunk = blockIdx.x & (NCH - 1);
    size_t cb = (size_t)chunk * (NPIX / NCH);
    const float* xr = x + (size_t)img * 3 * NPIX;
    int lane = threadIdx.x & 63, wv = threadIdx.x >> 6;

    float4 Rv[2], Gv[2], Bv[2];
#pragma unroll
    for (int j = 0; j < 2; ++j) {
        size_t off = cb + ((size_t)j * NTHR + threadIdx.x) * 4;
        Rv[j] = *(const float4*)(xr + off);
        Gv[j] = *(const float4*)(xr + NPIX + off);
        Bv[j] = *(const float4*)(xr + 2 * NPIX + off);
    }

    __shared__ double bmean;
    if (wv == 0) {
        size_t b0 = (size_t)img * NCH;
        double sg = p1[(b0 + lane) * NP1] + p1[(b0 + lane + 64) * NP1];
        sg = wredd(sg);
        if (lane == 0) bmean = sg / (double)NPIX;
    }
    __syncthreads();
    float mean = (float)bmean;

    float sa = 0.0f, sax = 0.0f, say = 0.0f;
#pragma unroll
    for (int j = 0; j < 2; ++j) {
        size_t off = cb + ((size_t)j * NTHR + threadIdx.x) * 4;
        float gv[4];
        gv[0] = 0.299f * Rv[j].x + 0.587f * Gv[j].x + 0.114f * Bv[j].x;
        gv[1] = 0.299f * Rv[j].y + 0.587f * Gv[j].y + 0.114f * Bv[j].y;
        gv[2] = 0.299f * Rv[j].z + 0.587f * Gv[j].z + 0.114f * Bv[j].z;
        gv[3] = 0.299f * Rv[j].w + 0.587f * Gv[j].w + 0.114f * Bv[j].w;
        float v = (float)(int)(off >> 9) - CTR;
        float u0 = (float)(int)(off & 511) - CTR;
#pragma unroll
        for (int u = 0; u < 4; ++u) {
            float a = fabsf(gv[u] - mean);
            sa += a;
            sax += a * (u0 + (float)u);
            say += a * v;
        }
    }
    {
        __shared__ double lds2[4][3];
        float acc[3] = {sa, sax, say};
#pragma unroll
        for (int a = 0; a < 3; ++a) {
            double s = wredd((double)acc[a]);
            if (lane == 0) lds2[wv][a] = s;
        }
        __syncthreads();
        if (threadIdx.x < 3)
            p2[((size_t)img * NCH + chunk) * 3 + threadIdx.x] =
                lds2[0][threadIdx.x] + lds2[1][threadIdx.x] + lds2[2][threadIdx.x] + lds2[3][threadIdx.x];
    }
    __syncthreads();

    // fire-and-forget: 128th arriver for this image finalizes
    __shared__ int is_last;
    if (threadIdx.x == 0) {
        __threadfence();
        int old = atomicAdd(&ctr[img], 1);
        is_last = (old == NCH - 1);
    }
    __syncthreads();
    if (!is_last || threadIdx.x >= 64) return;

    __threadfence();
    size_t b0 = (size_t)img * NCH;
    double M[11], B[3];
#pragma unroll
    for (int a = 0; a < 11; ++a)
        M[a] = aload(&p1[(b0 + lane) * NP1 + a]) + aload(&p1[(b0 + lane + 64) * NP1 + a]);
#pragma unroll
    for (int a = 0; a < 3; ++a)
        B[a] = aload(&p2[(b0 + lane) * 3 + a]) + aload(&p2[(b0 + lane + 64) * 3 + a]);
#pragma unroll
    for (int a = 0; a < 11; ++a) M[a] = wredd(M[a]);
#pragma unroll
    for (int a = 0; a < 3; ++a) B[a] = wredd(B[a]);

    if (lane == 0) {
        const double N = (double)NPIX;
        double G00 = M[0], Sg2 = M[1];
        double G10 = M[2], G01 = M[3], G20 = M[4], G11 = M[5], G02 = M[6];
        double G30 = M[7], G21 = M[8], G12 = M[9], G03 = M[10];
        double A0 = B[0], Ax = B[1], Ay = B[2];

        double mean2 = G00 / N;
        double var = Sg2 / N - mean2 * mean2;
        if (var < 0.0) var = 0.0;
        double inv_std = 1.0 / (sqrt(var) + 1e-8);

        double s_chk = A0 * inv_std;
        double dx, dy;  // cx-255.5, cy-255.5
        if (s_chk < 1e-8) { dx = 0.5; dy = 0.5; }
        else { dx = Ax / A0; dy = Ay / A0; }

        double S2 = 512.0 * (512.0 * 512.0 - 1.0) / 12.0;
        double P20 = S2 * 512.0, P02 = S2 * 512.0;

        double W00 = G00 - mean2 * N;
        double W10 = G10, W01 = G01;
        double W20 = G20 - mean2 * P20;
        double W11 = G11;
        double W02 = G02 - mean2 * P02;
        double W30 = G30, W21 = G21, W12 = G12, W03 = G03;

        double N00 = W00;
        double N10 = W10 - dx * W00;
        double N01 = W01 - dy * W00;
        double N20 = W20 - 2.0 * dx * W10 + dx * dx * W00;
        double N11 = W11 - dx * W01 - dy * W10 + dx * dy * W00;
        double N02 = W02 - 2.0 * dy * W01 + dy * dy * W00;
        double N30 = W30 - 3.0 * dx * W20 + 3.0 * dx * dx * W10 - dx * dx * dx * W00;
        double N21 = W21 - dy * W20 - 2.0 * dx * W11 + 2.0 * dx * dy * W10
                   + dx * dx * W01 - dx * dx * dy * W00;
        double N12 = W12 - dx * W02 - 2.0 * dy * W11 + 2.0 * dx * dy * W01
                   + dy * dy * W10 - dx * dy * dy * W00;
        double N03 = W03 - 3.0 * dy * W02 + 3.0 * dy * dy * W01 - dy * dy * dy * W00;

        double cx = (double)CTR + dx, cy = (double)CTR + dy;
        double mdx = fmax(cx, 511.0 - cx), mdy = fmax(cy, 511.0 - cy);
        double max_r = sqrt(mdx * mdx + mdy * mdy) + 1e-8;
        double imr = 1.0 / max_r;
        double im1 = inv_std * imr, im2 = im1 * imr, im3 = im2 * imr;
        double inv_denom = 1.0 / (max_r * max_r + 1e-8);

        double S0 = N00 * inv_std;
        double R2 = (N20 + N02) * im2;
        double C1 = N10 * im1, S1 = N01 * im1;
        double C2 = (N20 - N02) * im2, Sm2 = 2.0 * N11 * im2;
        double C3 = (N30 - 3.0 * N12) * im3, Sm3 = (3.0 * N21 - N03) * im3;
        double C31 = (N30 + N12) * im3, S31 = (N21 + N03) * im3;

        double f0 = fabs(S0) * inv_denom;
        double f1 = sqrt(C1 * C1 + S1 * S1) * inv_denom;
        double f3 = sqrt(C2 * C2 + Sm2 * Sm2) * inv_denom;
        double f4 = fabs(2.0 * R2 - S0) * inv_denom;
        double f6 = sqrt(C3 * C3 + Sm3 * Sm3) * inv_denom;
        double a31r = 3.0 * C31 - 2.0 * C1, a31i = 3.0 * S31 - 2.0 * S1;
        double f7 = sqrt(a31r * a31r + a31i * a31i) * inv_denom;

        float* o = out + (size_t)img * 20;
        o[0] = (float)f0;
        o[1] = (float)f1; o[2] = (float)f1;
        o[3] = (float)f3; o[4] = (float)f4; o[5] = (float)f3;
        o[6] = (float)f6; o[7] = (float)f7; o[8] = (float)f7; o[9] = (float)f6;
        for (int k = 10; k < 20; ++k) o[k] = 0.0f;
    }
}

extern "C" void kernel_launch(void* const* d_in, const int* in_sizes, int n_in,
                              void* d_out, int out_size, void* d_ws, size_t ws_size,
                              hipStream_t stream) {
    const float* x = (const float*)d_in[0];
    float* out = (float*)d_out;

    int* ctr = (int*)d_ws;                               // 64 ints
    double* p1 = (double*)((char*)d_ws + 256);           // 32*128*12 doubles
    double* p2 = p1 + (size_t)NIMG * NCH * NP1;          // 32*128*3 doubles

    dim3 grid(NIMG * NCH);
    k1<<<grid, NTHR, 0, stream>>>(x, p1, ctr);
    k2fin<<<grid, NTHR, 0, stream>>>(x, p1, p2, ctr, out);
}

// Round 10
// 56.665 us; speedup vs baseline: 3.2059x; 3.2059x over previous
//
#include <hip/hip_runtime.h>

#define NPIX (512*512)
#define NIMG 32
#define CTR 255.5f
#define NCH 64            // chunks (blocks) per image
#define NTHR 256
#define PLANE (NIMG*NCH)  // p1 plane stride (2048)

__device__ __forceinline__ double wredd(double v) {
#pragma unroll
    for (int off = 32; off; off >>= 1) v += __shfl_down(v, off, 64);
    return v;
}

// K1: raw moments, 2048 blocks x 256 thr, 16 px/thread, 12 float4 batched.
// p1 layout plane-major: p1[a*PLANE + img*NCH + chunk]. Block 0 zeroes the
// per-image accumulators + counters used by k2fin (k2 starts after k1 drains).
__global__ __launch_bounds__(NTHR) void k1(const float* __restrict__ x,
                                           double* __restrict__ p1,
                                           double* __restrict__ p2g,
                                           int* __restrict__ ctr) {
    if (blockIdx.x == 0) {
        if (threadIdx.x < 96) p2g[threadIdx.x] = 0.0;
        else if (threadIdx.x < 128) ctr[threadIdx.x - 96] = 0;
    }

    int img = blockIdx.x >> 6;
    int chunk = blockIdx.x & (NCH - 1);
    size_t cb = (size_t)chunk * (NPIX / NCH);   // 4096 px per chunk
    const float* xr = x + (size_t)img * 3 * NPIX;

    float4 Rv[4], Gv[4], Bv[4];
#pragma unroll
    for (int j = 0; j < 4; ++j) {
        size_t off = cb + ((size_t)j * NTHR + threadIdx.x) * 4;
        Rv[j] = *(const float4*)(xr + off);
        Gv[j] = *(const float4*)(xr + NPIX + off);
        Bv[j] = *(const float4*)(xr + 2 * NPIX + off);
    }

    float A[11];
#pragma unroll
    for (int a = 0; a < 11; ++a) A[a] = 0.0f;

#pragma unroll
    for (int j = 0; j < 4; ++j) {
        size_t off = cb + ((size_t)j * NTHR + threadIdx.x) * 4;
        float gv[4];
        gv[0] = 0.299f * Rv[j].x + 0.587f * Gv[j].x + 0.114f * Bv[j].x;
        gv[1] = 0.299f * Rv[j].y + 0.587f * Gv[j].y + 0.114f * Bv[j].y;
        gv[2] = 0.299f * Rv[j].z + 0.587f * Gv[j].z + 0.114f * Bv[j].z;
        gv[3] = 0.299f * Rv[j].w + 0.587f * Gv[j].w + 0.114f * Bv[j].w;
        float v = (float)(int)(off >> 9) - CTR;
        float v2 = v * v, v3 = v2 * v;
        float u0 = (float)(int)(off & 511) - CTR;
#pragma unroll
        for (int u = 0; u < 4; ++u) {
            float gg = gv[u];
            float uu = u0 + (float)u;
            float t1 = gg * uu, t2 = t1 * uu, t3 = t2 * uu;
            A[0] += gg;
            A[1] += gg * gg;
            A[2] += t1;
            A[3] += gg * v;
            A[4] += t2;
            A[5] += t1 * v;
            A[6] += gg * v2;
            A[7] += t3;
            A[8] += t2 * v;
            A[9] += t1 * v2;
            A[10] += gg * v3;
        }
    }

    __shared__ double lds[4][11];
    int lane = threadIdx.x & 63, wv = threadIdx.x >> 6;
#pragma unroll
    for (int a = 0; a < 11; ++a) {
        double s = wredd((double)A[a]);
        if (lane == 0) lds[wv][a] = s;
    }
    __syncthreads();
    if (threadIdx.x < 11)
        p1[(size_t)threadIdx.x * PLANE + (size_t)img * NCH + chunk] =
            lds[0][threadIdx.x] + lds[1][threadIdx.x] + lds[2][threadIdx.x] + lds[3][threadIdx.x];
}

// K2fin: |g-mean| block sums -> 3 fp64 atomicAdds per block (coherence point,
// NO threadfence); 64th-arriving block per image finalizes.
__global__ __launch_bounds__(NTHR) void k2fin(const float* __restrict__ x,
                                              const double* __restrict__ p1,
                                              double* __restrict__ p2g,
                                              int* __restrict__ ctr,
                                              float* __restrict__ out) {
    int img = blockIdx.x >> 6;
    int chunk = blockIdx.x & (NCH - 1);
    size_t cb = (size_t)chunk * (NPIX / NCH);
    const float* xr = x + (size_t)img * 3 * NPIX;
    int lane = threadIdx.x & 63, wv = threadIdx.x >> 6;

    float4 Rv[4], Gv[4], Bv[4];
#pragma unroll
    for (int j = 0; j < 4; ++j) {
        size_t off = cb + ((size_t)j * NTHR + threadIdx.x) * 4;
        Rv[j] = *(const float4*)(xr + off);
        Gv[j] = *(const float4*)(xr + NPIX + off);
        Bv[j] = *(const float4*)(xr + 2 * NPIX + off);
    }

    __shared__ double bmean;
    if (wv == 0) {
        double sg = p1[(size_t)img * NCH + lane];   // plane 0, contiguous 512B
        sg = wredd(sg);
        if (lane == 0) bmean = sg / (double)NPIX;
    }
    __syncthreads();
    float mean = (float)bmean;

    float sa = 0.0f, sax = 0.0f, say = 0.0f;
#pragma unroll
    for (int j = 0; j < 4; ++j) {
        size_t off = cb + ((size_t)j * NTHR + threadIdx.x) * 4;
        float gv[4];
        gv[0] = 0.299f * Rv[j].x + 0.587f * Gv[j].x + 0.114f * Bv[j].x;
        gv[1] = 0.299f * Rv[j].y + 0.587f * Gv[j].y + 0.114f * Bv[j].y;
        gv[2] = 0.299f * Rv[j].z + 0.587f * Gv[j].z + 0.114f * Bv[j].z;
        gv[3] = 0.299f * Rv[j].w + 0.587f * Gv[j].w + 0.114f * Bv[j].w;
        float v = (float)(int)(off >> 9) - CTR;
        float u0 = (float)(int)(off & 511) - CTR;
#pragma unroll
        for (int u = 0; u < 4; ++u) {
            float a = fabsf(gv[u] - mean);
            sa += a;
            sax += a * (u0 + (float)u);
            say += a * v;
        }
    }
    __shared__ double lds2[4][3];
    {
        float acc[3] = {sa, sax, say};
#pragma unroll
        for (int a = 0; a < 3; ++a) {
            double s = wredd((double)acc[a]);
            if (lane == 0) lds2[wv][a] = s;
        }
    }
    __syncthreads();
    if (threadIdx.x < 3) {
        double s = lds2[0][threadIdx.x] + lds2[1][threadIdx.x]
                 + lds2[2][threadIdx.x] + lds2[3][threadIdx.x];
        atomicAdd(&p2g[img * 3 + threadIdx.x], s);   // coherent, no fence
    }
    __syncthreads();                                  // drains the atomics

    __shared__ int is_last;
    if (threadIdx.x == 0)
        is_last = (atomicAdd(&ctr[img], 1) == NCH - 1);
    __syncthreads();
    if (!is_last || threadIdx.x >= 64) return;

    // ---- finalize (one wave). p1 from previous dispatch: plain loads OK.
    double M[11];
#pragma unroll
    for (int a = 0; a < 11; ++a)
        M[a] = p1[(size_t)a * PLANE + (size_t)img * NCH + lane];
#pragma unroll
    for (int a = 0; a < 11; ++a) M[a] = wredd(M[a]);

    if (lane == 0) {
        double B[3];
#pragma unroll
        for (int a = 0; a < 3; ++a)
            B[a] = __hip_atomic_load(&p2g[img * 3 + a], __ATOMIC_RELAXED,
                                     __HIP_MEMORY_SCOPE_AGENT);
        const double N = (double)NPIX;
        double G00 = M[0], Sg2 = M[1];
        double G10 = M[2], G01 = M[3], G20 = M[4], G11 = M[5], G02 = M[6];
        double G30 = M[7], G21 = M[8], G12 = M[9], G03 = M[10];
        double A0 = B[0], Ax = B[1], Ay = B[2];

        double mean2 = G00 / N;
        double var = Sg2 / N - mean2 * mean2;
        if (var < 0.0) var = 0.0;
        double inv_std = 1.0 / (sqrt(var) + 1e-8);

        double s_chk = A0 * inv_std;
        double dx, dy;  // cx-255.5, cy-255.5
        if (s_chk < 1e-8) { dx = 0.5; dy = 0.5; }
        else { dx = Ax / A0; dy = Ay / A0; }

        double S2 = 512.0 * (512.0 * 512.0 - 1.0) / 12.0;
        double P20 = S2 * 512.0, P02 = S2 * 512.0;

        double W00 = G00 - mean2 * N;
        double W10 = G10, W01 = G01;
        double W20 = G20 - mean2 * P20;
        double W11 = G11;
        double W02 = G02 - mean2 * P02;
        double W30 = G30, W21 = G21, W12 = G12, W03 = G03;

        double N00 = W00;
        double N10 = W10 - dx * W00;
        double N01 = W01 - dy * W00;
        double N20 = W20 - 2.0 * dx * W10 + dx * dx * W00;
        double N11 = W11 - dx * W01 - dy * W10 + dx * dy * W00;
        double N02 = W02 - 2.0 * dy * W01 + dy * dy * W00;
        double N30 = W30 - 3.0 * dx * W20 + 3.0 * dx * dx * W10 - dx * dx * dx * W00;
        double N21 = W21 - dy * W20 - 2.0 * dx * W11 + 2.0 * dx * dy * W10
                   + dx * dx * W01 - dx * dx * dy * W00;
        double N12 = W12 - dx * W02 - 2.0 * dy * W11 + 2.0 * dx * dy * W01
                   + dy * dy * W10 - dx * dy * dy * W00;
        double N03 = W03 - 3.0 * dy * W02 + 3.0 * dy * dy * W01 - dy * dy * dy * W00;

        double cx = (double)CTR + dx, cy = (double)CTR + dy;
        double mdx = fmax(cx, 511.0 - cx), mdy = fmax(cy, 511.0 - cy);
        double max_r = sqrt(mdx * mdx + mdy * mdy) + 1e-8;
        double imr = 1.0 / max_r;
        double im1 = inv_std * imr, im2 = im1 * imr, im3 = im2 * imr;
        double inv_denom = 1.0 / (max_r * max_r + 1e-8);

        double S0 = N00 * inv_std;
        double R2 = (N20 + N02) * im2;
        double C1 = N10 * im1, S1 = N01 * im1;
        double C2 = (N20 - N02) * im2, Sm2 = 2.0 * N11 * im2;
        double C3 = (N30 - 3.0 * N12) * im3, Sm3 = (3.0 * N21 - N03) * im3;
        double C31 = (N30 + N12) * im3, S31 = (N21 + N03) * im3;

        double f0 = fabs(S0) * inv_denom;
        double f1 = sqrt(C1 * C1 + S1 * S1) * inv_denom;
        double f3 = sqrt(C2 * C2 + Sm2 * Sm2) * inv_denom;
        double f4 = fabs(2.0 * R2 - S0) * inv_denom;
        double f6 = sqrt(C3 * C3 + Sm3 * Sm3) * inv_denom;
        double a31r = 3.0 * C31 - 2.0 * C1, a31i = 3.0 * S31 - 2.0 * S1;
        double f7 = sqrt(a31r * a31r + a31i * a31i) * inv_denom;

        float* o = out + (size_t)img * 20;
        o[0] = (float)f0;
        o[1] = (float)f1; o[2] = (float)f1;
        o[3] = (float)f3; o[4] = (float)f4; o[5] = (float)f3;
        o[6] = (float)f6; o[7] = (float)f7; o[8] = (float)f7; o[9] = (float)f6;
        for (int k = 10; k < 20; ++k) o[k] = 0.0f;
    }
}

extern "C" void kernel_launch(void* const* d_in, const int* in_sizes, int n_in,
                              void* d_out, int out_size, void* d_ws, size_t ws_size,
                              hipStream_t stream) {
    const float* x = (const float*)d_in[0];
    float* out = (float*)d_out;

    double* p2g = (double*)d_ws;                          // 96 doubles
    int* ctr = (int*)((char*)d_ws + 1024);                // 32 ints
    double* p1 = (double*)((char*)d_ws + 2048);           // 11*2048 doubles

    dim3 grid(NIMG * NCH);
    k1<<<grid, NTHR, 0, stream>>>(x, p1, p2g, ctr);
    k2fin<<<grid, NTHR, 0, stream>>>(x, p1, p2g, ctr, out);
}